// Round 7
// baseline (308.111 us; speedup 1.0000x reference)
//
#include <hip/hip_runtime.h>

#define N_NODES 50000
#define N_EDGES 800000
#define BN_EPS 1e-5f
#define NB 196          // dst buckets: bucket = dst >> 8
#define BCAP 5120       // bucket capacity (avg 4082, sigma ~64)
#define SCAT_BLOCKS 100 // 8000 edges per block

typedef __bf16 bf16x8 __attribute__((ext_vector_type(8)));
typedef float f32x4 __attribute__((ext_vector_type(4)));

static __device__ __forceinline__ unsigned short f2b(float f) {
    unsigned int u = __float_as_uint(f);
    return (unsigned short)((u + 0x7FFFu + ((u >> 16) & 1u)) >> 16);   // RNE
}
static __device__ __forceinline__ float bl(unsigned int u) { return __uint_as_float(u << 16); }
static __device__ __forceinline__ float bh(unsigned int u) { return __uint_as_float(u & 0xFFFF0000u); }

// ---------------------------------------------------------------------------
// CSR build via dense-write bucket sort
// ---------------------------------------------------------------------------
__global__ void init_gcur(int* __restrict__ gcur) {
    int t = threadIdx.x;
    if (t < NB) gcur[t] = t * BCAP;
}

__global__ __launch_bounds__(256) void bucket_scatter(const int* __restrict__ ei,
                                                      int* __restrict__ gcur,
                                                      unsigned int* __restrict__ bdata) {
    __shared__ int hist[NB];
    __shared__ int lcur[NB];
    int t = threadIdx.x;
    if (t < NB) hist[t] = 0;
    __syncthreads();
    int e0 = blockIdx.x * 8000;
    for (int i = t; i < 8000; i += 256) {
        int d = ei[N_EDGES + e0 + i];
        atomicAdd(&hist[d >> 8], 1);
    }
    __syncthreads();
    if (t < NB) lcur[t] = atomicAdd(&gcur[t], hist[t]);
    __syncthreads();
    for (int i = t; i < 8000; i += 256) {
        int d = ei[N_EDGES + e0 + i];
        int s = ei[e0 + i];
        int b = d >> 8;
        int p = atomicAdd(&lcur[b], 1);
        if (p < (b + 1) * BCAP)                       // capacity guard
            bdata[p] = (unsigned int)s | ((unsigned int)(d & 255) << 16);
    }
}

__global__ __launch_bounds__(256) void scan_buckets(const int* __restrict__ gcur,
                                                    int* __restrict__ bbase,
                                                    int* __restrict__ row) {
    __shared__ int sm[256];
    int t = threadIdx.x;
    int v = 0;
    if (t < NB) {
        v = gcur[t] - t * BCAP;
        if (v > BCAP) v = BCAP;
    }
    sm[t] = v;
    __syncthreads();
    int x = v;
    for (int off = 1; off < 256; off <<= 1) {
        int y = (t >= off) ? sm[t - off] : 0;
        __syncthreads();
        x += y;
        sm[t] = x;
        __syncthreads();
    }
    if (t < NB) bbase[t] = x - v;   // exclusive
    if (t == 0) row[N_NODES] = N_EDGES;
}

// One block per bucket: local count + scan + fill, all writes dense & block-local.
__global__ __launch_bounds__(256) void bucket_fill(const unsigned int* __restrict__ bdata,
                                                   const int* __restrict__ gcur,
                                                   const int* __restrict__ bbase,
                                                   int* __restrict__ row,
                                                   int* __restrict__ csrc) {
    __shared__ unsigned int ent[BCAP];
    __shared__ int lcnt[256];
    __shared__ int sm[256];
    __shared__ int cur[256];
    int b = blockIdx.x;
    int t = threadIdx.x;
    int cnt = gcur[b] - b * BCAP;
    if (cnt > BCAP) cnt = BCAP;
    int base = bbase[b];
    for (int i = t; i < cnt; i += 256) ent[i] = bdata[b * BCAP + i];
    lcnt[t] = 0;
    __syncthreads();
    for (int i = t; i < cnt; i += 256) atomicAdd(&lcnt[(ent[i] >> 16) & 255], 1);
    __syncthreads();
    int v = lcnt[t];
    sm[t] = v;
    __syncthreads();
    int x = v;
    for (int off = 1; off < 256; off <<= 1) {
        int y = (t >= off) ? sm[t - off] : 0;
        __syncthreads();
        x += y;
        sm[t] = x;
        __syncthreads();
    }
    int pre = x - v;
    int node = b * 256 + t;
    if (node < N_NODES) row[node] = base + pre;
    cur[t] = base + pre;
    __syncthreads();
    for (int i = t; i < cnt; i += 256) {
        unsigned int e = ent[i];
        int p = atomicAdd(&cur[(e >> 16) & 255], 1);
        csrc[p] = (int)(e & 0xFFFFu);
    }
}

// ---------------------------------------------------------------------------
// Casts
// ---------------------------------------------------------------------------
__global__ __launch_bounds__(256) void cast_x(const float* __restrict__ in,
                                              unsigned short* __restrict__ out) {
    int idx = blockIdx.x * 256 + threadIdx.x;          // float4 chunk
    if (idx >= N_NODES * 32) return;
    float4 v = ((const float4*)in)[idx];
    uint2 p;
    p.x = (unsigned int)f2b(v.x) | ((unsigned int)f2b(v.y) << 16);
    p.y = (unsigned int)f2b(v.z) | ((unsigned int)f2b(v.w) << 16);
    ((uint2*)out)[idx] = p;
}

__global__ void wcast(const float* __restrict__ Wl1, const float* __restrict__ Wr1,
                      const float* __restrict__ Wl2, const float* __restrict__ Wr2,
                      const float* __restrict__ Wl3, const float* __restrict__ Wr3,
                      unsigned short* __restrict__ out) {
    int idx = blockIdx.x * 256 + threadIdx.x;
    if (idx >= 81920) return;
    float v;
    if (idx < 16384)       v = Wl1[idx];
    else if (idx < 32768)  v = Wr1[idx - 16384];
    else if (idx < 49152)  v = Wl2[idx - 32768];
    else if (idx < 65536)  v = Wr2[idx - 49152];
    else if (idx < 73728)  v = Wl3[idx - 65536];
    else                   v = Wr3[idx - 73728];
    out[idx] = f2b(v);
}

// ---------------------------------------------------------------------------
// Fused layer: gather-mean (+prev BN/ReLU) -> LDS A-tile -> MFMA dual-GEMM
// (+bias, +column stats). Block = 256 thr, 64 output rows.
// A-tile XOR-swizzled (16B slot ^= row&7) so MFMA-phase ds_read_b128 across
// 16 rows is conflict-free. Each wave owns 64 rows x (O/4) cols -> only
// 2*NFW*4 W-fragments/lane, hoisted to registers from L2-hot weights.
// ---------------------------------------------------------------------------
template <int O, bool STATS, bool ACT, bool BF16OUT>
__global__ __launch_bounds__(256) void fused_layer(const unsigned short* __restrict__ xin,
                                                   const int* __restrict__ row,
                                                   const int* __restrict__ csrc,
                                                   const float* __restrict__ scl,
                                                   const float* __restrict__ shf,
                                                   const unsigned short* __restrict__ Wl,
                                                   const unsigned short* __restrict__ Wr,
                                                   const float* __restrict__ bias,
                                                   unsigned short* __restrict__ hout,
                                                   float* __restrict__ fout,
                                                   float* __restrict__ cs,
                                                   float* __restrict__ cq) {
    constexpr int NFW = O / 64;              // col-frags per wave
    __shared__ uint2 atile[2][64][32];       // [mean|self][row][swizzled 8B pos]
    __shared__ float colsum[O], colsq[O];
    int t = threadIdx.x;
    int rbase = blockIdx.x * 64;

    if (STATS && t < O) {
        colsum[t] = 0.f;
        colsq[t] = 0.f;
    }

    // ---- gather phase: half-wave per node, 8 nodes each ----
    {
        int half = t >> 5, hl = t & 31;
        float4 sc{}, sh{};
        if (ACT) {
            sc = ((const float4*)scl)[hl];
            sh = ((const float4*)shf)[hl];
        }
        const uint2* x2 = (const uint2*)xin;
        auto val = [&](float raw, float s, float h) {
            return ACT ? fmaxf(fmaf(raw, s, h), 0.f) : raw;
        };
        for (int it = 0; it < 8; ++it) {
            int nl = half * 8 + it;
            int node = rbase + nl;
            uint2 pk = {0u, 0u}, sp = {0u, 0u};
            if (node < N_NODES) {
                int r0 = row[node], r1 = row[node + 1];
                float a0 = 0.f, a1 = 0.f, a2 = 0.f, a3 = 0.f;
                int j = r0;
                for (; j + 1 < r1; j += 2) {
                    int s0 = csrc[j], s1 = csrc[j + 1];
                    uint2 v0 = x2[(size_t)s0 * 32 + hl];
                    uint2 v1 = x2[(size_t)s1 * 32 + hl];
                    a0 += val(bl(v0.x), sc.x, sh.x) + val(bl(v1.x), sc.x, sh.x);
                    a1 += val(bh(v0.x), sc.y, sh.y) + val(bh(v1.x), sc.y, sh.y);
                    a2 += val(bl(v0.y), sc.z, sh.z) + val(bl(v1.y), sc.z, sh.z);
                    a3 += val(bh(v0.y), sc.w, sh.w) + val(bh(v1.y), sc.w, sh.w);
                }
                if (j < r1) {
                    uint2 v = x2[(size_t)csrc[j] * 32 + hl];
                    a0 += val(bl(v.x), sc.x, sh.x);
                    a1 += val(bh(v.x), sc.y, sh.y);
                    a2 += val(bl(v.y), sc.z, sh.z);
                    a3 += val(bh(v.y), sc.w, sh.w);
                }
                int deg = r1 - r0;
                float inv = 1.0f / (float)(deg > 1 ? deg : 1);
                pk.x = (unsigned int)f2b(a0 * inv) | ((unsigned int)f2b(a1 * inv) << 16);
                pk.y = (unsigned int)f2b(a2 * inv) | ((unsigned int)f2b(a3 * inv) << 16);
                uint2 v = x2[(size_t)node * 32 + hl];
                if (ACT) {
                    float e0 = val(bl(v.x), sc.x, sh.x), e1 = val(bh(v.x), sc.y, sh.y);
                    float e2 = val(bl(v.y), sc.z, sh.z), e3 = val(bh(v.y), sc.w, sh.w);
                    sp.x = (unsigned int)f2b(e0) | ((unsigned int)f2b(e1) << 16);
                    sp.y = (unsigned int)f2b(e2) | ((unsigned int)f2b(e3) << 16);
                } else {
                    sp = v;
                }
            }
            int sw = hl ^ ((nl & 7) << 1);   // 16B-slot swizzle in 8B units
            atile[0][nl][sw] = pk;
            atile[1][nl][sw] = sp;
        }
    }

    // ---- W fragments -> registers (weights are L2-hot, 16 indep loads) ----
    int wv = t >> 6, l = t & 63;
    int lr = l & 15, ko = l >> 4;
    int cbase = wv * (16 * NFW);
    bf16x8 wfl[NFW][4], wfr[NFW][4];
#pragma unroll
    for (int nf = 0; nf < NFW; ++nf)
#pragma unroll
        for (int ks = 0; ks < 4; ++ks) {
            size_t woff = (size_t)(cbase + nf * 16 + lr) * 128 + ks * 32 + ko * 8;
            wfl[nf][ks] = *(const bf16x8*)(Wl + woff);
            wfr[nf][ks] = *(const bf16x8*)(Wr + woff);
        }

    __syncthreads();

    // ---- MFMA: 4 row-tiles x NFW col-frags ----
    f32x4 acc[4][NFW];
#pragma unroll
    for (int tt = 0; tt < 4; ++tt)
#pragma unroll
        for (int nf = 0; nf < NFW; ++nf) acc[tt][nf] = (f32x4){0.f, 0.f, 0.f, 0.f};

    int rsw = (lr & 7) << 1;
#pragma unroll
    for (int tt = 0; tt < 4; ++tt) {
        int r = tt * 16 + lr;
#pragma unroll
        for (int ks = 0; ks < 4; ++ks) {
            int uidx = ((ks * 4 + ko) << 1) ^ rsw;
            bf16x8 am = *(const bf16x8*)&atile[0][r][uidx];
            bf16x8 ax = *(const bf16x8*)&atile[1][r][uidx];
#pragma unroll
            for (int nf = 0; nf < NFW; ++nf) {
                acc[tt][nf] = __builtin_amdgcn_mfma_f32_16x16x32_bf16(am, wfl[nf][ks], acc[tt][nf], 0, 0, 0);
                acc[tt][nf] = __builtin_amdgcn_mfma_f32_16x16x32_bf16(ax, wfr[nf][ks], acc[tt][nf], 0, 0, 0);
            }
        }
    }

    // ---- epilogue: bias + store + fused column stats ----
#pragma unroll
    for (int tt = 0; tt < 4; ++tt) {
        int orow0 = rbase + tt * 16 + ko * 4;
#pragma unroll
        for (int nf = 0; nf < NFW; ++nf) {
            int col = cbase + nf * 16 + lr;
            float bs = bias[col];
            float s = 0.f, q = 0.f;
#pragma unroll
            for (int j = 0; j < 4; ++j) {
                int r = orow0 + j;
                if (r < N_NODES) {
                    float v = acc[tt][nf][j] + bs;
                    if (BF16OUT) hout[(size_t)r * 128 + col] = f2b(v);
                    else         fout[(size_t)r * 64 + col] = v;
                    s += v;
                    q += v * v;
                }
            }
            if (STATS) {
                s += __shfl_xor(s, 16);
                s += __shfl_xor(s, 32);
                q += __shfl_xor(q, 16);
                q += __shfl_xor(q, 32);
                if (ko == 0) {
                    atomicAdd(&colsum[col], s);
                    atomicAdd(&colsq[col], q);
                }
            }
        }
    }
    if (STATS) {
        __syncthreads();
        if (t < O) {
            atomicAdd(&cs[t], colsum[t]);
            atomicAdd(&cq[t], colsq[t]);
        }
    }
}

__global__ void bn_prep(const float* __restrict__ cs, const float* __restrict__ cq,
                        const float* __restrict__ g, const float* __restrict__ be,
                        float* __restrict__ scale, float* __restrict__ shift) {
    int f = threadIdx.x;
    float mu = cs[f] * (1.0f / N_NODES);
    float var = cq[f] * (1.0f / N_NODES) - mu * mu;
    float sc = g[f] * rsqrtf(var + BN_EPS);
    scale[f] = sc;
    shift[f] = be[f] - mu * sc;
}

// ---------------------------------------------------------------------------
extern "C" void kernel_launch(void* const* d_in, const int* in_sizes, int n_in,
                              void* d_out, int out_size, void* d_ws, size_t ws_size,
                              hipStream_t stream) {
    const float* x   = (const float*)d_in[0];
    const int*   ei  = (const int*)d_in[1];
    const float* Wl1 = (const float*)d_in[2];
    const float* Wr1 = (const float*)d_in[3];
    const float* b1  = (const float*)d_in[4];
    const float* g1  = (const float*)d_in[5];
    const float* be1 = (const float*)d_in[6];
    const float* Wl2 = (const float*)d_in[7];
    const float* Wr2 = (const float*)d_in[8];
    const float* b2  = (const float*)d_in[9];
    const float* g2  = (const float*)d_in[10];
    const float* be2 = (const float*)d_in[11];
    const float* Wl3 = (const float*)d_in[12];
    const float* Wr3 = (const float*)d_in[13];
    const float* b3  = (const float*)d_in[14];
    float* out = (float*)d_out;

    char* p = (char*)d_ws;
    size_t off = 0;
    auto alloc = [&](size_t bytes) {
        char* r = p + off;
        off = (off + bytes + 255) & ~(size_t)255;
        return r;
    };
    int*            gcur  = (int*)alloc((size_t)NB * 4);
    int*            bbase = (int*)alloc((size_t)NB * 4);
    unsigned int*   bdata = (unsigned int*)alloc((size_t)NB * BCAP * 4);
    int*            row   = (int*)alloc((size_t)(N_NODES + 1) * 4);
    int*            csrc  = (int*)alloc((size_t)N_EDGES * 4);
    unsigned short* xb    = (unsigned short*)alloc((size_t)N_NODES * 128 * 2);
    unsigned short* h1    = (unsigned short*)alloc((size_t)N_NODES * 128 * 2);
    unsigned short* h2    = (unsigned short*)alloc((size_t)N_NODES * 128 * 2);
    unsigned short* wbf   = (unsigned short*)alloc((size_t)81920 * 2);
    float*          cs    = (float*)alloc(256 * 4);   // cs[128] | cq[128]
    float*          cq    = cs + 128;
    float*          scl1  = (float*)alloc(128 * 4);
    float*          shf1  = (float*)alloc(128 * 4);
    float*          scl2  = (float*)alloc(128 * 4);
    float*          shf2  = (float*)alloc(128 * 4);
    (void)ws_size; (void)n_in; (void)in_sizes; (void)out_size;

    unsigned short* wl1b = wbf;
    unsigned short* wr1b = wbf + 16384;
    unsigned short* wl2b = wbf + 32768;
    unsigned short* wr2b = wbf + 49152;
    unsigned short* wl3b = wbf + 65536;
    unsigned short* wr3b = wbf + 73728;

    const int FBLK = (N_NODES + 63) / 64;           // 782
    const int CBLK = (N_NODES * 32 + 255) / 256;    // 6250

    // casts + CSR build (dense-write bucket sort)
    cast_x<<<CBLK, 256, 0, stream>>>(x, xb);
    wcast<<<320, 256, 0, stream>>>(Wl1, Wr1, Wl2, Wr2, Wl3, Wr3, wbf);
    init_gcur<<<1, 256, 0, stream>>>(gcur);
    bucket_scatter<<<SCAT_BLOCKS, 256, 0, stream>>>(ei, gcur, bdata);
    scan_buckets<<<1, 256, 0, stream>>>(gcur, bbase, row);
    bucket_fill<<<NB, 256, 0, stream>>>(bdata, gcur, bbase, row, csrc);

    // Layer 1: gather(xb) + GEMM + stats -> h1
    hipMemsetAsync(cs, 0, 256 * 4, stream);
    fused_layer<128, true, false, true><<<FBLK, 256, 0, stream>>>(
        xb, row, csrc, nullptr, nullptr, wl1b, wr1b, b1, h1, nullptr, cs, cq);
    bn_prep<<<1, 128, 0, stream>>>(cs, cq, g1, be1, scl1, shf1);

    // Layer 2: gather(h1, BN1+ReLU fused) + GEMM + stats -> h2
    hipMemsetAsync(cs, 0, 256 * 4, stream);
    fused_layer<128, true, true, true><<<FBLK, 256, 0, stream>>>(
        h1, row, csrc, scl1, shf1, wl2b, wr2b, b2, h2, nullptr, cs, cq);
    bn_prep<<<1, 128, 0, stream>>>(cs, cq, g2, be2, scl2, shf2);

    // Layer 3: gather(h2, BN2+ReLU fused) + GEMM -> f32 d_out
    fused_layer<64, false, true, false><<<FBLK, 256, 0, stream>>>(
        h2, row, csrc, scl2, shf2, wl3b, wr3b, b3, nullptr, out, nullptr, nullptr);
}